// Round 3
// baseline (51696.075 us; speedup 1.0000x reference)
//
#include <hip/hip_runtime.h>

// 2-layer LSTM (B=4096, T=512, H=50) + FC head, fp32.
// R3: k split 8-ways (was 4) to halve weight VGPRs -> no scratch spill.
// Block = 512 threads = 64 padded units (n) x 8 k-slices (ko, 8 k each).
// Each thread: 16 batches. Grid = 256 blocks (1/CU, 8 waves = 2/SIMD).
// Regs: weights 96 + acc 64 + c 32 + temps ~= 220 < 256.
// Reduce over ko: DPP quad_perm xor1/xor2 + ds_swizzle xor4 (0x101F).

#define LOG2E 1.44269504088896340736f

template <int CTRL>
__device__ __forceinline__ float dppf(float v) {
  return __int_as_float(
      __builtin_amdgcn_mov_dpp(__float_as_int(v), CTRL, 0xf, 0xf, true));
}
__device__ __forceinline__ float swz_xor4(float v) {
  // ds_swizzle BitMode: new_lane = lane ^ 4  (offset = (4<<10) | 0x1F)
  return __int_as_float(__builtin_amdgcn_ds_swizzle(__float_as_int(v), 0x101F));
}
// sum over the 8 ko lanes (lane bits 0..2)
__device__ __forceinline__ float qsum8(float v) {
  v += dppf<0xB1>(v);   // xor 1 (quad_perm [1,0,3,2])
  v += dppf<0x4E>(v);   // xor 2 (quad_perm [2,3,0,1])
  v += swz_xor4(v);     // xor 4 (ds_swizzle)
  return v;
}

__device__ __forceinline__ float sigm(float x) {
  return __builtin_amdgcn_rcpf(1.f + __builtin_amdgcn_exp2f(-LOG2E * x));
}
__device__ __forceinline__ float tanh_(float x) {
  return 1.f - 2.f * __builtin_amdgcn_rcpf(1.f + __builtin_amdgcn_exp2f(2.f * LOG2E * x));
}
__device__ __forceinline__ void fma4(float4& a, float s, const float4& w) {
  a.x += s * w.x; a.y += s * w.y; a.z += s * w.z; a.w += s * w.w;
}

__global__ __launch_bounds__(512, 1) void lstm2_kernel(
    const float* __restrict__ x,
    const float* __restrict__ Wih0, const float* __restrict__ Whh0,
    const float* __restrict__ bih0, const float* __restrict__ bhh0,
    const float* __restrict__ Wih1, const float* __restrict__ Whh1,
    const float* __restrict__ bih1, const float* __restrict__ bhh1,
    const float* __restrict__ fcW, const float* __restrict__ fcb,
    float* __restrict__ out) {
  const int tid = threadIdx.x;
  const int n  = tid >> 3;  // padded unit 0..63 (>=50 dummy)
  const int ko = tid & 7;   // k-slice (8 k each)
  const int bbase = blockIdx.x * 16;

  __shared__ float h0s[2][16][72];  // [parity][batch][padded unit (+8 pad)]
  __shared__ float h1s[2][16][72];
  __shared__ float xs[16][65];      // x chunk: 16 batch x 64 t (+1 pad)

  for (int i = tid; i < 2 * 16 * 72; i += 512) {
    ((float*)h0s)[i] = 0.f;
    ((float*)h1s)[i] = 0.f;
  }

  // ---- per-lane weight slices: w*[j][kk] = float4 over gates {i,f,g,o}
  //      at k = 8*ko + 4*j + kk,  j in [0,2), kk in [0,4)
  float4 w0g[2][4], w1ig[2][4], w1hg[2][4];
  const bool nv = (n < 50);
#pragma unroll
  for (int j = 0; j < 2; ++j) {
#pragma unroll
    for (int kk = 0; kk < 4; ++kk) {
      const int k = 8 * ko + 4 * j + kk;
      const bool kv = nv && (k < 50);
      float4 a, b, c;
      a.x = kv ? Whh0[(0 * 50 + n) * 50 + k] : 0.f;
      a.y = kv ? Whh0[(1 * 50 + n) * 50 + k] : 0.f;
      a.z = kv ? Whh0[(2 * 50 + n) * 50 + k] : 0.f;
      a.w = kv ? Whh0[(3 * 50 + n) * 50 + k] : 0.f;
      b.x = kv ? Wih1[(0 * 50 + n) * 50 + k] : 0.f;
      b.y = kv ? Wih1[(1 * 50 + n) * 50 + k] : 0.f;
      b.z = kv ? Wih1[(2 * 50 + n) * 50 + k] : 0.f;
      b.w = kv ? Wih1[(3 * 50 + n) * 50 + k] : 0.f;
      c.x = kv ? Whh1[(0 * 50 + n) * 50 + k] : 0.f;
      c.y = kv ? Whh1[(1 * 50 + n) * 50 + k] : 0.f;
      c.z = kv ? Whh1[(2 * 50 + n) * 50 + k] : 0.f;
      c.w = kv ? Whh1[(3 * 50 + n) * 50 + k] : 0.f;
      w0g[j][kk] = a; w1ig[j][kk] = b; w1hg[j][kk] = c;
    }
  }
  float4 bb0, bb1, wx0;
  bb0.x = nv ? (bih0[0 * 50 + n] + bhh0[0 * 50 + n]) : 0.f;
  bb0.y = nv ? (bih0[1 * 50 + n] + bhh0[1 * 50 + n]) : 0.f;
  bb0.z = nv ? (bih0[2 * 50 + n] + bhh0[2 * 50 + n]) : 0.f;
  bb0.w = nv ? (bih0[3 * 50 + n] + bhh0[3 * 50 + n]) : 0.f;
  bb1.x = nv ? (bih1[0 * 50 + n] + bhh1[0 * 50 + n]) : 0.f;
  bb1.y = nv ? (bih1[1 * 50 + n] + bhh1[1 * 50 + n]) : 0.f;
  bb1.z = nv ? (bih1[2 * 50 + n] + bhh1[2 * 50 + n]) : 0.f;
  bb1.w = nv ? (bih1[3 * 50 + n] + bhh1[3 * 50 + n]) : 0.f;
  wx0.x = nv ? Wih0[0 * 50 + n] : 0.f;
  wx0.y = nv ? Wih0[1 * 50 + n] : 0.f;
  wx0.z = nv ? Wih0[2 * 50 + n] : 0.f;
  wx0.w = nv ? Wih0[3 * 50 + n] : 0.f;

  float c0[16], c1[16];
#pragma unroll
  for (int b = 0; b < 16; ++b) { c0[b] = 0.f; c1[b] = 0.f; }

  for (int t = 0; t < 512; ++t) {
    if ((t & 63) == 0) {  // stage next 64 timesteps of x
      __syncthreads();
      {
        int i = tid, sb = i >> 6, st = i & 63;
        xs[sb][st] = x[(size_t)(bbase + sb) * 512 + t + st];
        i = tid + 512; sb = i >> 6; st = i & 63;
        xs[sb][st] = x[(size_t)(bbase + sb) * 512 + t + st];
      }
      __syncthreads();
    }
    const int rp = (t + 1) & 1;
    const int wp = t & 1;
    const int tm = t & 63;

    // ================= layer 0 =================
    float4 acc[16];
#pragma unroll
    for (int b = 0; b < 16; ++b) acc[b] = make_float4(0.f, 0.f, 0.f, 0.f);
#pragma unroll
    for (int j = 0; j < 2; ++j) {
      const int koff = 8 * ko + 4 * j;
#pragma unroll
      for (int b = 0; b < 16; ++b) {
        const float4 hf = *(const float4*)&h0s[rp][b][koff];
        fma4(acc[b], hf.x, w0g[j][0]);
        fma4(acc[b], hf.y, w0g[j][1]);
        fma4(acc[b], hf.z, w0g[j][2]);
        fma4(acc[b], hf.w, w0g[j][3]);
      }
    }
#pragma unroll
    for (int b = 0; b < 16; ++b) {
      const float xv = xs[b][tm];
      float gi = sigm(qsum8(acc[b].x) + bb0.x + xv * wx0.x);
      float gf = sigm(qsum8(acc[b].y) + bb0.y + xv * wx0.y);
      float gg = tanh_(qsum8(acc[b].z) + bb0.z + xv * wx0.z);
      float go = sigm(qsum8(acc[b].w) + bb0.w + xv * wx0.w);
      const float c = gf * c0[b] + gi * gg;
      c0[b] = c;
      const float h = go * tanh_(c);
      if (ko == (b >> 1)) h0s[wp][b][n] = h;  // lane ko owns batches 2ko,2ko+1
    }
    __syncthreads();

    // ================= layer 1 =================
#pragma unroll
    for (int b = 0; b < 16; ++b) acc[b] = make_float4(0.f, 0.f, 0.f, 0.f);
#pragma unroll
    for (int j = 0; j < 2; ++j) {
      const int koff = 8 * ko + 4 * j;
#pragma unroll
      for (int b = 0; b < 16; ++b) {
        const float4 hf0 = *(const float4*)&h0s[wp][b][koff];
        const float4 hf1 = *(const float4*)&h1s[rp][b][koff];
        fma4(acc[b], hf0.x, w1ig[j][0]);
        fma4(acc[b], hf0.y, w1ig[j][1]);
        fma4(acc[b], hf0.z, w1ig[j][2]);
        fma4(acc[b], hf0.w, w1ig[j][3]);
        fma4(acc[b], hf1.x, w1hg[j][0]);
        fma4(acc[b], hf1.y, w1hg[j][1]);
        fma4(acc[b], hf1.z, w1hg[j][2]);
        fma4(acc[b], hf1.w, w1hg[j][3]);
      }
    }
#pragma unroll
    for (int b = 0; b < 16; ++b) {
      float gi = sigm(qsum8(acc[b].x) + bb1.x);
      float gf = sigm(qsum8(acc[b].y) + bb1.y);
      float gg = tanh_(qsum8(acc[b].z) + bb1.z);
      float go = sigm(qsum8(acc[b].w) + bb1.w);
      const float c = gf * c1[b] + gi * gg;
      c1[b] = c;
      const float h = go * tanh_(c);
      if (ko == (b >> 1)) h1s[wp][b][n] = h;
    }
    __syncthreads();
  }

  // ---- FC head ----
  if (tid < 16) {
    float s = fcb[0];
    for (int j = 0; j < 50; ++j) s += fcW[j] * h1s[1][tid][j];  // t=511 -> parity 1
    out[bbase + tid] = s;
  }
}

extern "C" void kernel_launch(void* const* d_in, const int* in_sizes, int n_in,
                              void* d_out, int out_size, void* d_ws, size_t ws_size,
                              hipStream_t stream) {
  const float* x    = (const float*)d_in[0];
  const float* Wih0 = (const float*)d_in[1];
  const float* Whh0 = (const float*)d_in[2];
  const float* bih0 = (const float*)d_in[3];
  const float* bhh0 = (const float*)d_in[4];
  const float* Wih1 = (const float*)d_in[5];
  const float* Whh1 = (const float*)d_in[6];
  const float* bih1 = (const float*)d_in[7];
  const float* bhh1 = (const float*)d_in[8];
  const float* fcW  = (const float*)d_in[9];
  const float* fcb  = (const float*)d_in[10];
  float* out = (float*)d_out;

  const int B = out_size;          // 4096
  const int blocks = B / 16;       // 256
  lstm2_kernel<<<dim3(blocks), dim3(512), 0, stream>>>(
      x, Wih0, Whh0, bih0, bhh0, Wih1, Whh1, bih1, bhh1, fcW, fcb, out);
}

// Round 4
// 8243.571 us; speedup vs baseline: 6.2711x; 6.2711x over previous
//
#include <hip/hip_runtime.h>

// 2-layer LSTM (B=4096, T=512, H=50) + FC head, fp32.
// R4: same 8-way k-split as R3, but
//  (a) amdgpu_waves_per_eu(2,2) pins exactly 2 waves/SIMD -> 256-VGPR cap,
//      stopping the allocator from self-capping at 128 and spilling (R3:
//      VGPR_Count=128, 45 GB scratch traffic, VALUBusy 11%).
//  (b) batches processed in two halves of 8 reusing float4 acc[8]
//      -> true demand ~195 regs, ~60 regs of slack under the cap.
// Block = 512 threads = 64 padded units (n) x 8 k-slices (ko, 8 k each).
// 16 batches/block, 256 blocks (1/CU). Reduce over ko: DPP xor1/xor2 +
// ds_swizzle xor4.

#define LOG2E 1.44269504088896340736f

template <int CTRL>
__device__ __forceinline__ float dppf(float v) {
  return __int_as_float(
      __builtin_amdgcn_mov_dpp(__float_as_int(v), CTRL, 0xf, 0xf, true));
}
__device__ __forceinline__ float swz_xor4(float v) {
  // ds_swizzle BitMode: new_lane = lane ^ 4  (offset = (4<<10) | 0x1F)
  return __int_as_float(__builtin_amdgcn_ds_swizzle(__float_as_int(v), 0x101F));
}
// sum over the 8 ko lanes (lane bits 0..2)
__device__ __forceinline__ float qsum8(float v) {
  v += dppf<0xB1>(v);   // xor 1 (quad_perm [1,0,3,2])
  v += dppf<0x4E>(v);   // xor 2 (quad_perm [2,3,0,1])
  v += swz_xor4(v);     // xor 4 (ds_swizzle)
  return v;
}

__device__ __forceinline__ float sigm(float x) {
  return __builtin_amdgcn_rcpf(1.f + __builtin_amdgcn_exp2f(-LOG2E * x));
}
__device__ __forceinline__ float tanh_(float x) {
  return 1.f - 2.f * __builtin_amdgcn_rcpf(1.f + __builtin_amdgcn_exp2f(2.f * LOG2E * x));
}
__device__ __forceinline__ void fma4(float4& a, float s, const float4& w) {
  a.x += s * w.x; a.y += s * w.y; a.z += s * w.z; a.w += s * w.w;
}

__global__ __launch_bounds__(512)
__attribute__((amdgpu_waves_per_eu(2, 2)))
void lstm2_kernel(
    const float* __restrict__ x,
    const float* __restrict__ Wih0, const float* __restrict__ Whh0,
    const float* __restrict__ bih0, const float* __restrict__ bhh0,
    const float* __restrict__ Wih1, const float* __restrict__ Whh1,
    const float* __restrict__ bih1, const float* __restrict__ bhh1,
    const float* __restrict__ fcW, const float* __restrict__ fcb,
    float* __restrict__ out) {
  const int tid = threadIdx.x;
  const int n  = tid >> 3;  // padded unit 0..63 (>=50 dummy)
  const int ko = tid & 7;   // k-slice (8 k each)
  const int bbase = blockIdx.x * 16;

  __shared__ float h0s[2][16][72];  // [parity][batch][padded unit (+8 pad)]
  __shared__ float h1s[2][16][72];
  __shared__ float xs[16][65];      // x chunk: 16 batch x 64 t (+1 pad)

  for (int i = tid; i < 2 * 16 * 72; i += 512) {
    ((float*)h0s)[i] = 0.f;
    ((float*)h1s)[i] = 0.f;
  }

  // ---- per-lane weight slices: w*[j][kk] = float4 over gates {i,f,g,o}
  //      at k = 8*ko + 4*j + kk,  j in [0,2), kk in [0,4)
  float4 w0g[2][4], w1ig[2][4], w1hg[2][4];
  const bool nv = (n < 50);
#pragma unroll
  for (int j = 0; j < 2; ++j) {
#pragma unroll
    for (int kk = 0; kk < 4; ++kk) {
      const int k = 8 * ko + 4 * j + kk;
      const bool kv = nv && (k < 50);
      float4 a, b, c;
      a.x = kv ? Whh0[(0 * 50 + n) * 50 + k] : 0.f;
      a.y = kv ? Whh0[(1 * 50 + n) * 50 + k] : 0.f;
      a.z = kv ? Whh0[(2 * 50 + n) * 50 + k] : 0.f;
      a.w = kv ? Whh0[(3 * 50 + n) * 50 + k] : 0.f;
      b.x = kv ? Wih1[(0 * 50 + n) * 50 + k] : 0.f;
      b.y = kv ? Wih1[(1 * 50 + n) * 50 + k] : 0.f;
      b.z = kv ? Wih1[(2 * 50 + n) * 50 + k] : 0.f;
      b.w = kv ? Wih1[(3 * 50 + n) * 50 + k] : 0.f;
      c.x = kv ? Whh1[(0 * 50 + n) * 50 + k] : 0.f;
      c.y = kv ? Whh1[(1 * 50 + n) * 50 + k] : 0.f;
      c.z = kv ? Whh1[(2 * 50 + n) * 50 + k] : 0.f;
      c.w = kv ? Whh1[(3 * 50 + n) * 50 + k] : 0.f;
      w0g[j][kk] = a; w1ig[j][kk] = b; w1hg[j][kk] = c;
    }
  }
  float4 bb0, bb1, wx0;
  bb0.x = nv ? (bih0[0 * 50 + n] + bhh0[0 * 50 + n]) : 0.f;
  bb0.y = nv ? (bih0[1 * 50 + n] + bhh0[1 * 50 + n]) : 0.f;
  bb0.z = nv ? (bih0[2 * 50 + n] + bhh0[2 * 50 + n]) : 0.f;
  bb0.w = nv ? (bih0[3 * 50 + n] + bhh0[3 * 50 + n]) : 0.f;
  bb1.x = nv ? (bih1[0 * 50 + n] + bhh1[0 * 50 + n]) : 0.f;
  bb1.y = nv ? (bih1[1 * 50 + n] + bhh1[1 * 50 + n]) : 0.f;
  bb1.z = nv ? (bih1[2 * 50 + n] + bhh1[2 * 50 + n]) : 0.f;
  bb1.w = nv ? (bih1[3 * 50 + n] + bhh1[3 * 50 + n]) : 0.f;
  wx0.x = nv ? Wih0[0 * 50 + n] : 0.f;
  wx0.y = nv ? Wih0[1 * 50 + n] : 0.f;
  wx0.z = nv ? Wih0[2 * 50 + n] : 0.f;
  wx0.w = nv ? Wih0[3 * 50 + n] : 0.f;

  float c0[16], c1[16];
#pragma unroll
  for (int b = 0; b < 16; ++b) { c0[b] = 0.f; c1[b] = 0.f; }

  for (int t = 0; t < 512; ++t) {
    if ((t & 63) == 0) {  // stage next 64 timesteps of x
      __syncthreads();
      {
        int i = tid, sb = i >> 6, st = i & 63;
        xs[sb][st] = x[(size_t)(bbase + sb) * 512 + t + st];
        i = tid + 512; sb = i >> 6; st = i & 63;
        xs[sb][st] = x[(size_t)(bbase + sb) * 512 + t + st];
      }
      __syncthreads();
    }
    const int rp = (t + 1) & 1;
    const int wp = t & 1;
    const int tm = t & 63;

    // ================= layer 0 =================
#pragma unroll
    for (int half = 0; half < 2; ++half) {
      float4 acc[8];
#pragma unroll
      for (int bb = 0; bb < 8; ++bb) acc[bb] = make_float4(0.f, 0.f, 0.f, 0.f);
#pragma unroll
      for (int j = 0; j < 2; ++j) {
        const int koff = 8 * ko + 4 * j;
#pragma unroll
        for (int bb = 0; bb < 8; ++bb) {
          const int b = half * 8 + bb;
          const float4 hf = *(const float4*)&h0s[rp][b][koff];
          fma4(acc[bb], hf.x, w0g[j][0]);
          fma4(acc[bb], hf.y, w0g[j][1]);
          fma4(acc[bb], hf.z, w0g[j][2]);
          fma4(acc[bb], hf.w, w0g[j][3]);
        }
      }
#pragma unroll
      for (int bb = 0; bb < 8; ++bb) {
        const int b = half * 8 + bb;
        const float xv = xs[b][tm];
        float gi = sigm(qsum8(acc[bb].x) + bb0.x + xv * wx0.x);
        float gf = sigm(qsum8(acc[bb].y) + bb0.y + xv * wx0.y);
        float gg = tanh_(qsum8(acc[bb].z) + bb0.z + xv * wx0.z);
        float go = sigm(qsum8(acc[bb].w) + bb0.w + xv * wx0.w);
        const float c = gf * c0[b] + gi * gg;
        c0[b] = c;
        const float h = go * tanh_(c);
        if (ko == (b >> 1)) h0s[wp][b][n] = h;  // lane ko owns 2 batches
      }
    }
    __syncthreads();

    // ================= layer 1 =================
#pragma unroll
    for (int half = 0; half < 2; ++half) {
      float4 acc[8];
#pragma unroll
      for (int bb = 0; bb < 8; ++bb) acc[bb] = make_float4(0.f, 0.f, 0.f, 0.f);
#pragma unroll
      for (int j = 0; j < 2; ++j) {
        const int koff = 8 * ko + 4 * j;
#pragma unroll
        for (int bb = 0; bb < 8; ++bb) {
          const int b = half * 8 + bb;
          const float4 hf0 = *(const float4*)&h0s[wp][b][koff];
          const float4 hf1 = *(const float4*)&h1s[rp][b][koff];
          fma4(acc[bb], hf0.x, w1ig[j][0]);
          fma4(acc[bb], hf0.y, w1ig[j][1]);
          fma4(acc[bb], hf0.z, w1ig[j][2]);
          fma4(acc[bb], hf0.w, w1ig[j][3]);
          fma4(acc[bb], hf1.x, w1hg[j][0]);
          fma4(acc[bb], hf1.y, w1hg[j][1]);
          fma4(acc[bb], hf1.z, w1hg[j][2]);
          fma4(acc[bb], hf1.w, w1hg[j][3]);
        }
      }
#pragma unroll
      for (int bb = 0; bb < 8; ++bb) {
        const int b = half * 8 + bb;
        float gi = sigm(qsum8(acc[bb].x) + bb1.x);
        float gf = sigm(qsum8(acc[bb].y) + bb1.y);
        float gg = tanh_(qsum8(acc[bb].z) + bb1.z);
        float go = sigm(qsum8(acc[bb].w) + bb1.w);
        const float c = gf * c1[b] + gi * gg;
        c1[b] = c;
        const float h = go * tanh_(c);
        if (ko == (b >> 1)) h1s[wp][b][n] = h;
      }
    }
    __syncthreads();
  }

  // ---- FC head ----
  if (tid < 16) {
    float s = fcb[0];
    for (int j = 0; j < 50; ++j) s += fcW[j] * h1s[1][tid][j];  // t=511 -> parity 1
    out[bbase + tid] = s;
  }
}

extern "C" void kernel_launch(void* const* d_in, const int* in_sizes, int n_in,
                              void* d_out, int out_size, void* d_ws, size_t ws_size,
                              hipStream_t stream) {
  const float* x    = (const float*)d_in[0];
  const float* Wih0 = (const float*)d_in[1];
  const float* Whh0 = (const float*)d_in[2];
  const float* bih0 = (const float*)d_in[3];
  const float* bhh0 = (const float*)d_in[4];
  const float* Wih1 = (const float*)d_in[5];
  const float* Whh1 = (const float*)d_in[6];
  const float* bih1 = (const float*)d_in[7];
  const float* bhh1 = (const float*)d_in[8];
  const float* fcW  = (const float*)d_in[9];
  const float* fcb  = (const float*)d_in[10];
  float* out = (float*)d_out;

  const int B = out_size;          // 4096
  const int blocks = B / 16;       // 256
  lstm2_kernel<<<dim3(blocks), dim3(512), 0, stream>>>(
      x, Wih0, Whh0, bih0, bhh0, Wih1, Whh1, bih1, bhh1, fcW, fcb, out);
}

// Round 5
// 3563.866 us; speedup vs baseline: 14.5056x; 2.3131x over previous
//
#include <hip/hip_runtime.h>

// 2-layer LSTM (B=4096, T=512, H=50) + FC head, fp32.
// R5 changes vs R4 (which passed at 8.24 ms but spilled ~40 regs):
//  (a) LDS occupancy pin: +64 KB pad array -> 88 KB/block -> only 1 block/CU
//      fits -> register allocator budget becomes 256 VGPRs (R2-R4 evidence:
//      allocator always targets 2 blocks/CU and spills to get there, while
//      the grid only ever runs 1 block/CU).
//  (b) Owner-finish: after the broadcast butterfly reduce, a 7-cndmask tree
//      selects A[ko] so each lane finishes ONE batch (was: every lane
//      finished all 8 redundantly -> 8x TRANS + 28 extra c-state regs).
// Structure: 256 blocks x 16 batches. Block = 512 thr = 64 units x 8 k-slices.
// Weights in VGPRs (96), h0/h1 via dbuf LDS, reduce = DPP xor1/xor2 + swizzle xor4.

#define LOG2E 1.44269504088896340736f

template <int CTRL>
__device__ __forceinline__ float dppf(float v) {
  return __int_as_float(
      __builtin_amdgcn_mov_dpp(__float_as_int(v), CTRL, 0xf, 0xf, true));
}
__device__ __forceinline__ float swz_xor4(float v) {
  // ds_swizzle BitMode: new_lane = lane ^ 4  (offset = (4<<10) | 0x1F)
  return __int_as_float(__builtin_amdgcn_ds_swizzle(__float_as_int(v), 0x101F));
}
template <int CTRL>
__device__ __forceinline__ void hop_dpp4(float4& a) {
  a.x += dppf<CTRL>(a.x); a.y += dppf<CTRL>(a.y);
  a.z += dppf<CTRL>(a.z); a.w += dppf<CTRL>(a.w);
}
__device__ __forceinline__ void hop_swz4(float4& a) {
  a.x += swz_xor4(a.x); a.y += swz_xor4(a.y);
  a.z += swz_xor4(a.z); a.w += swz_xor4(a.w);
}
__device__ __forceinline__ float4 sel4(bool c, const float4& a, const float4& b) {
  return make_float4(c ? a.x : b.x, c ? a.y : b.y, c ? a.z : b.z, c ? a.w : b.w);
}
__device__ __forceinline__ float sigm(float x) {
  return __builtin_amdgcn_rcpf(1.f + __builtin_amdgcn_exp2f(-LOG2E * x));
}
__device__ __forceinline__ float tanh_(float x) {
  return 1.f - 2.f * __builtin_amdgcn_rcpf(1.f + __builtin_amdgcn_exp2f(2.f * LOG2E * x));
}
__device__ __forceinline__ void fma4(float4& a, float s, const float4& w) {
  a.x += s * w.x; a.y += s * w.y; a.z += s * w.z; a.w += s * w.w;
}

__global__ __launch_bounds__(512)
void lstm2_kernel(
    const float* __restrict__ x,
    const float* __restrict__ Wih0, const float* __restrict__ Whh0,
    const float* __restrict__ bih0, const float* __restrict__ bhh0,
    const float* __restrict__ Wih1, const float* __restrict__ Whh1,
    const float* __restrict__ bih1, const float* __restrict__ bhh1,
    const float* __restrict__ fcW, const float* __restrict__ fcb,
    float* __restrict__ out) {
  const int tid = threadIdx.x;
  const int n  = tid >> 3;  // padded unit 0..63 (>=50 dummy)
  const int ko = tid & 7;   // k-slice (8 k each)
  const int bbase = blockIdx.x * 16;

  __shared__ float h0s[2][16][72];  // [parity][batch][padded unit (+8 pad)]
  __shared__ float h1s[2][16][72];
  __shared__ float xs[16][65];      // x chunk: 16 batch x 64 t (+1 pad)
  __shared__ float ldspad[16384];   // occupancy pin: 64 KB -> 1 block/CU

  ((volatile float*)ldspad)[tid] = 0.f;  // keep the pad alive (never read)

  for (int i = tid; i < 2 * 16 * 72; i += 512) {
    ((float*)h0s)[i] = 0.f;
    ((float*)h1s)[i] = 0.f;
  }

  // ---- per-lane weight slices: w*[j][kk] = float4 over gates {i,f,g,o}
  //      at k = 8*ko + 4*j + kk
  float4 w0g[2][4], w1ig[2][4], w1hg[2][4];
  const bool nv = (n < 50);
#pragma unroll
  for (int j = 0; j < 2; ++j) {
#pragma unroll
    for (int kk = 0; kk < 4; ++kk) {
      const int k = 8 * ko + 4 * j + kk;
      const bool kv = nv && (k < 50);
      float4 a, b, c;
      a.x = kv ? Whh0[(0 * 50 + n) * 50 + k] : 0.f;
      a.y = kv ? Whh0[(1 * 50 + n) * 50 + k] : 0.f;
      a.z = kv ? Whh0[(2 * 50 + n) * 50 + k] : 0.f;
      a.w = kv ? Whh0[(3 * 50 + n) * 50 + k] : 0.f;
      b.x = kv ? Wih1[(0 * 50 + n) * 50 + k] : 0.f;
      b.y = kv ? Wih1[(1 * 50 + n) * 50 + k] : 0.f;
      b.z = kv ? Wih1[(2 * 50 + n) * 50 + k] : 0.f;
      b.w = kv ? Wih1[(3 * 50 + n) * 50 + k] : 0.f;
      c.x = kv ? Whh1[(0 * 50 + n) * 50 + k] : 0.f;
      c.y = kv ? Whh1[(1 * 50 + n) * 50 + k] : 0.f;
      c.z = kv ? Whh1[(2 * 50 + n) * 50 + k] : 0.f;
      c.w = kv ? Whh1[(3 * 50 + n) * 50 + k] : 0.f;
      w0g[j][kk] = a; w1ig[j][kk] = b; w1hg[j][kk] = c;
    }
  }
  float4 bb0, bb1, wx0;
  bb0.x = nv ? (bih0[0 * 50 + n] + bhh0[0 * 50 + n]) : 0.f;
  bb0.y = nv ? (bih0[1 * 50 + n] + bhh0[1 * 50 + n]) : 0.f;
  bb0.z = nv ? (bih0[2 * 50 + n] + bhh0[2 * 50 + n]) : 0.f;
  bb0.w = nv ? (bih0[3 * 50 + n] + bhh0[3 * 50 + n]) : 0.f;
  bb1.x = nv ? (bih1[0 * 50 + n] + bhh1[0 * 50 + n]) : 0.f;
  bb1.y = nv ? (bih1[1 * 50 + n] + bhh1[1 * 50 + n]) : 0.f;
  bb1.z = nv ? (bih1[2 * 50 + n] + bhh1[2 * 50 + n]) : 0.f;
  bb1.w = nv ? (bih1[3 * 50 + n] + bhh1[3 * 50 + n]) : 0.f;
  wx0.x = nv ? Wih0[0 * 50 + n] : 0.f;
  wx0.y = nv ? Wih0[1 * 50 + n] : 0.f;
  wx0.z = nv ? Wih0[2 * 50 + n] : 0.f;
  wx0.w = nv ? Wih0[3 * 50 + n] : 0.f;

  // per-lane cell state: lane ko owns batch half*8+ko of each layer
  float c0own[2] = {0.f, 0.f};
  float c1own[2] = {0.f, 0.f};

  const bool s0 = (ko & 1) != 0, s1 = (ko & 2) != 0, s2 = (ko & 4) != 0;

  for (int t = 0; t < 512; ++t) {
    if ((t & 63) == 0) {  // stage next 64 timesteps of x
      __syncthreads();
      {
        int i = tid, sb = i >> 6, st = i & 63;
        xs[sb][st] = x[(size_t)(bbase + sb) * 512 + t + st];
        i = tid + 512; sb = i >> 6; st = i & 63;
        xs[sb][st] = x[(size_t)(bbase + sb) * 512 + t + st];
      }
      __syncthreads();
    }
    const int rp = (t + 1) & 1;
    const int wp = t & 1;
    const int tm = t & 63;
    const float* h0r = &h0s[rp][0][0];
    float*       h0w = &h0s[wp][0][0];
    const float* h1r = &h1s[rp][0][0];
    float*       h1w = &h1s[wp][0][0];

    // ================= layer 0 =================
#pragma unroll
    for (int half = 0; half < 2; ++half) {
      float4 A[8];
#pragma unroll
      for (int bb = 0; bb < 8; ++bb) A[bb] = make_float4(0.f, 0.f, 0.f, 0.f);
#pragma unroll
      for (int j = 0; j < 2; ++j) {
        const int koff = 8 * ko + 4 * j;
#pragma unroll
        for (int bb = 0; bb < 8; ++bb) {
          const float4 hf = *(const float4*)&h0r[(half * 8 + bb) * 72 + koff];
          fma4(A[bb], hf.x, w0g[j][0]);
          fma4(A[bb], hf.y, w0g[j][1]);
          fma4(A[bb], hf.z, w0g[j][2]);
          fma4(A[bb], hf.w, w0g[j][3]);
        }
      }
      // broadcast butterfly over the 8 ko lanes
#pragma unroll
      for (int bb = 0; bb < 8; ++bb) hop_dpp4<0xB1>(A[bb]);
#pragma unroll
      for (int bb = 0; bb < 8; ++bb) hop_dpp4<0x4E>(A[bb]);
#pragma unroll
      for (int bb = 0; bb < 8; ++bb) hop_swz4(A[bb]);
      // select A[ko]: lane ko finishes batch half*8+ko only
      const float4 B0 = sel4(s0, A[1], A[0]), B1 = sel4(s0, A[3], A[2]);
      const float4 B2 = sel4(s0, A[5], A[4]), B3 = sel4(s0, A[7], A[6]);
      const float4 C0 = sel4(s1, B1, B0),     C1 = sel4(s1, B3, B2);
      const float4 D  = sel4(s2, C1, C0);
      const int b = half * 8 + ko;
      const float xv = xs[b][tm];
      const float gi = sigm(D.x + bb0.x + xv * wx0.x);
      const float gf = sigm(D.y + bb0.y + xv * wx0.y);
      const float gg = tanh_(D.z + bb0.z + xv * wx0.z);
      const float go = sigm(D.w + bb0.w + xv * wx0.w);
      const float c = gf * c0own[half] + gi * gg;
      c0own[half] = c;
      h0w[b * 72 + n] = go * tanh_(c);
    }
    __syncthreads();  // h0[t] ready

    // ================= layer 1 =================
#pragma unroll
    for (int half = 0; half < 2; ++half) {
      float4 A[8];
#pragma unroll
      for (int bb = 0; bb < 8; ++bb) A[bb] = make_float4(0.f, 0.f, 0.f, 0.f);
#pragma unroll
      for (int j = 0; j < 2; ++j) {
        const int koff = 8 * ko + 4 * j;
#pragma unroll
        for (int bb = 0; bb < 8; ++bb) {
          const int b = half * 8 + bb;
          const float4 hf0 = *(const float4*)&h0w[b * 72 + koff];
          const float4 hf1 = *(const float4*)&h1r[b * 72 + koff];
          fma4(A[bb], hf0.x, w1ig[j][0]);
          fma4(A[bb], hf0.y, w1ig[j][1]);
          fma4(A[bb], hf0.z, w1ig[j][2]);
          fma4(A[bb], hf0.w, w1ig[j][3]);
          fma4(A[bb], hf1.x, w1hg[j][0]);
          fma4(A[bb], hf1.y, w1hg[j][1]);
          fma4(A[bb], hf1.z, w1hg[j][2]);
          fma4(A[bb], hf1.w, w1hg[j][3]);
        }
      }
#pragma unroll
      for (int bb = 0; bb < 8; ++bb) hop_dpp4<0xB1>(A[bb]);
#pragma unroll
      for (int bb = 0; bb < 8; ++bb) hop_dpp4<0x4E>(A[bb]);
#pragma unroll
      for (int bb = 0; bb < 8; ++bb) hop_swz4(A[bb]);
      const float4 B0 = sel4(s0, A[1], A[0]), B1 = sel4(s0, A[3], A[2]);
      const float4 B2 = sel4(s0, A[5], A[4]), B3 = sel4(s0, A[7], A[6]);
      const float4 C0 = sel4(s1, B1, B0),     C1 = sel4(s1, B3, B2);
      const float4 D  = sel4(s2, C1, C0);
      const int b = half * 8 + ko;
      const float gi = sigm(D.x + bb1.x);
      const float gf = sigm(D.y + bb1.y);
      const float gg = tanh_(D.z + bb1.z);
      const float go = sigm(D.w + bb1.w);
      const float c = gf * c1own[half] + gi * gg;
      c1own[half] = c;
      h1w[b * 72 + n] = go * tanh_(c);
    }
    __syncthreads();  // h1[t] ready; also guards next step's WAR
  }

  // ---- FC head ----
  if (tid < 16) {
    float s = fcb[0];
    for (int j = 0; j < 50; ++j) s += fcW[j] * h1s[1][tid][j];  // t=511 -> parity 1
    out[bbase + tid] = s;
  }
}

extern "C" void kernel_launch(void* const* d_in, const int* in_sizes, int n_in,
                              void* d_out, int out_size, void* d_ws, size_t ws_size,
                              hipStream_t stream) {
  const float* x    = (const float*)d_in[0];
  const float* Wih0 = (const float*)d_in[1];
  const float* Whh0 = (const float*)d_in[2];
  const float* bih0 = (const float*)d_in[3];
  const float* bhh0 = (const float*)d_in[4];
  const float* Wih1 = (const float*)d_in[5];
  const float* Whh1 = (const float*)d_in[6];
  const float* bih1 = (const float*)d_in[7];
  const float* bhh1 = (const float*)d_in[8];
  const float* fcW  = (const float*)d_in[9];
  const float* fcb  = (const float*)d_in[10];
  float* out = (float*)d_out;

  const int B = out_size;          // 4096
  const int blocks = B / 16;       // 256
  lstm2_kernel<<<dim3(blocks), dim3(512), 0, stream>>>(
      x, Wih0, Whh0, bih0, bhh0, Wih1, Whh1, bih1, bhh1, fcW, fcb, out);
}